// Round 15
// baseline (122.965 us; speedup 1.0000x reference)
//
#include <hip/hip_runtime.h>
#include <hip/hip_bf16.h>

#define SQ 2048
#define DD 64
#define NBH 64            // B*H
#define KVB 64
#define NT (SQ / KVB)     // 32 kv tiles
#define REC 16384         // per-(bh,tile): [K 8KB (8 chunks) | V 8KB (8 chunks)]
#define VOFF 8192
#define STG 8192          // staged bytes per tile (V only)
#define SCL 0.18033688011112042f   // 0.125 * log2(e); folded into Q

typedef __attribute__((ext_vector_type(8))) short bf16x8;
typedef __attribute__((ext_vector_type(4))) float f32x4;
typedef __attribute__((ext_vector_type(16))) float f32x16;

__device__ __forceinline__ short f2bf(float f) {
  union { float f; unsigned u; } un; un.f = f;
  unsigned r = un.u + 0x7fffu + ((un.u >> 16) & 1u);   // RNE
  return (short)(r >> 16);
}

__device__ __forceinline__ unsigned cvtpk(float lo, float hi) {
  unsigned d;
  asm("v_cvt_pk_bf16_f32 %0, %1, %2" : "=v"(d) : "v"(lo), "v"(hi));
  return d;
}

__device__ __forceinline__ void gld_lds16(const void* g, void* l) {
  __builtin_amdgcn_global_load_lds(
      (const __attribute__((address_space(1))) unsigned int*)g,
      (__attribute__((address_space(3))) unsigned int*)l, 16, 0, 0);
}

__device__ __forceinline__ f32x16 z16() {
  f32x16 z;
  #pragma unroll
  for (int i = 0; i < 16; ++i) z[i] = 0.f;
  return z;
}

// Record layout (load-order-major, per (bh,t)):
//   K chunk c = h*4+kk (0..7) at c*1024:  lane(l31,hi)*16B = bf16 K[h*32+l31][(2kk+hi)*8+j]
//   V chunk cid=kk*2+h (0..7) at 8192+cid*1024: lane(l31,hi)*16B =
//       bf16 V[kv][h*32+l31] (masked->0), kv = 8kk + 4hi + (j&3) + 32*(j>>2)
// All wave accesses (global or LDS) are contiguous 1KB at lane*16 -> conflict-free.

// ---------------- prepass: K,V fp32 -> load-order-major bf16 records ----------------
__global__ __launch_bounds__(256)
void prepack(const float* __restrict__ Kg, const float* __restrict__ Vg,
             const int* __restrict__ maskg, char* __restrict__ img)
{
  __shared__ float vst[64][68];
  const int bh = blockIdx.y, t = blockIdx.x;
  const size_t base = ((size_t)bh * SQ + (size_t)t * KVB) * DD;
  const int tid  = threadIdx.x;
  const int wv   = tid >> 6;
  const int lane = tid & 63;
  const int l31  = lane & 31;
  const int hi   = lane >> 5;
  char* rec = img + ((size_t)bh * NT + t) * REC;
  const int* mrow = maskg + (size_t)(bh >> 4) * SQ + t * KVB;
  unsigned long long mb = __ballot(mrow[lane] != 0);

  // stage V tile fp32 into LDS (coalesced)
  {
    int r = tid >> 2, c0 = (tid & 3) * 16;
    const float* g = Vg + base + (size_t)r * DD + c0;
    #pragma unroll
    for (int i = 0; i < 4; ++i)
      *(f32x4*)&vst[r][c0 + i * 4] = *(const f32x4*)&g[i * 4];
  }
  // K chunks: flat index c = wv*2 + i; h = c>>2, kk = c&3
  #pragma unroll
  for (int i = 0; i < 2; ++i) {
    int c = wv * 2 + i;            // 0..7
    int h = c >> 2, kk = c & 3;
    int r = h * 32 + l31;
    int col = (2 * kk + hi) * 8;
    const float* g = Kg + base + (size_t)r * DD + col;
    float tv[8];
    *(f32x4*)&tv[0] = *(const f32x4*)&g[0];
    *(f32x4*)&tv[4] = *(const f32x4*)&g[4];
    bf16x8 o;
    #pragma unroll
    for (int j = 0; j < 8; ++j) o[j] = f2bf(tv[j]);
    *(bf16x8*)(rec + c * 1024 + lane * 16) = o;
  }
  __syncthreads();
  // V chunks (kv-permuted, masked -> 0) -- verbatim R12/R13 layout
  #pragma unroll
  for (int i = 0; i < 2; ++i) {
    int cid = wv * 2 + i;          // 0..7
    int kk = cid >> 1, h = cid & 1;
    int d = h * 32 + l31;
    bf16x8 o;
    #pragma unroll
    for (int j = 0; j < 8; ++j) {
      int kv = 8 * kk + 4 * hi + (j & 3) + 32 * (j >> 2);
      o[j] = ((mb >> kv) & 1ull) ? (short)0 : f2bf(vst[kv][d]);
    }
    *(bf16x8*)(rec + VOFF + cid * 1024 + lane * 16) = o;
  }
}

// ---------------- main: all-K reg prefetch, V-only LDS dbuf, R13 barrier discipline ----------------
__global__ __launch_bounds__(256, 4)
void attn32(const char* __restrict__ img, const float* __restrict__ Qg,
            const int* __restrict__ maskg, float* __restrict__ Og)
{
  __shared__ char buf[2][STG];                     // V x2 = 16KB
  __shared__ __align__(16) short mones[NT][KVB];   // permuted per-tile ones/mask rows

  const int tid  = threadIdx.x;
  const int wv   = tid >> 6;
  const int lane = tid & 63;
  const int l31  = lane & 31;
  const int hi   = lane >> 5;

  // XCD-aware swizzle: 1024 blocks, 8 XCDs -> 128-block chunks (8 bh per XCD)
  const int bid = blockIdx.x;
  const int swz = (bid & 7) * 128 + (bid >> 3);
  const int qb = swz & 15;
  const int bh = swz >> 4;
  const int q0 = qb * 128 + wv * 32;
  const size_t base = (size_t)bh * SQ * DD;
  const char* rec0 = img + (size_t)bh * NT * REC;

  // ---- build permuted per-tile ones rows from mask (once per block) ----
  {
    const int* mrow = maskg + (size_t)(bh >> 4) * SQ;
    #pragma unroll
    for (int i = 0; i < 8; ++i) {
      int idx = tid + i * 256;           // 0..2047
      int t = idx >> 6, p = idx & 63;
      int kv = 8 * (p >> 4) + 4 * ((p >> 3) & 1) + (p & 3) + 32 * ((p >> 2) & 1);
      mones[t][p] = mrow[t * KVB + kv] ? (short)0 : (short)0x3F80;
    }
  }

  // Q fragments pre-scaled by SCL (B-operand: n = l31, k-slot j <-> d = kk*16 + hi*8 + j)
  bf16x8 qf[4];
  {
    const float* qrow = Qg + base + (size_t)(q0 + l31) * DD + hi * 8;
    #pragma unroll
    for (int kk = 0; kk < 4; ++kk) {
      float tv[8];
      *(f32x4*)&tv[0] = *(const f32x4*)&qrow[kk * 16];
      *(f32x4*)&tv[4] = *(const f32x4*)&qrow[kk * 16 + 4];
      #pragma unroll
      for (int j = 0; j < 8; ++j) qf[kk][j] = f2bf(tv[j] * SCL);
    }
  }

  const int loff = lane * 16;

  // prologue: all K of tile 0 into regs; stage V of tile 0 into buf0
  bf16x8 kreg[8];
  #pragma unroll
  for (int c = 0; c < 8; ++c)
    kreg[c] = *(const bf16x8*)(rec0 + c * 1024 + loff);
  #pragma unroll
  for (int i = 0; i < 2; ++i)
    gld_lds16(rec0 + VOFF + i * 4096 + tid * 16, buf[0] + i * 4096 + tid * 16);

  f32x16 accO0 = z16(), accO1 = z16(), acc2 = z16();

  int cur = 0;
  for (int t = 0; t < NT; ++t) {
    __syncthreads();   // buf[cur] staged (vmcnt drain); prior reads of buf[cur^1] done

    if (t + 1 < NT) {  // stage next V into the buffer prev PV finished with
      const char* rec = rec0 + (size_t)(t + 1) * REC;
      char* dst = buf[cur ^ 1];
      #pragma unroll
      for (int i = 0; i < 2; ++i)
        gld_lds16(rec + VOFF + i * 4096 + tid * 16, dst + i * 4096 + tid * 16);
    }

    // ---- S^T = K Q^T : entirely from registers ----
    f32x16 sA = z16(), sB = z16();
    #pragma unroll
    for (int kk = 0; kk < 4; ++kk) {
      sA = __builtin_amdgcn_mfma_f32_32x32x16_bf16(kreg[kk],     qf[kk], sA, 0, 0, 0);
      sB = __builtin_amdgcn_mfma_f32_32x32x16_bf16(kreg[4 + kk], qf[kk], sB, 0, 0, 0);
    }

    // ---- prefetch next tile's K into regs (window: exp2 + PV) ----
    if (t + 1 < NT) {
      const char* rec = rec0 + (size_t)(t + 1) * REC;
      #pragma unroll
      for (int c = 0; c < 8; ++c)
        kreg[c] = *(const bf16x8*)(rec + c * 1024 + loff);
    }

    // ---- P = exp2(s), static max folded away (exact 2^k shift cancels in O/l) ----
    #pragma unroll
    for (int r = 0; r < 16; ++r) {
      sA[r] = exp2f(sA[r]);
      sB[r] = exp2f(sB[r]);
    }

    // ---- PV + l-channel: A-fragment lane-local; V chunks linear in LDS ----
    const char* bk = buf[cur];
    const short* mrowt = &mones[t][0];
    #pragma unroll
    for (int kk = 0; kk < 4; ++kk) {
      union { unsigned u[4]; bf16x8 v; } pf;
      pf.u[0] = cvtpk(sA[4 * kk + 0], sA[4 * kk + 1]);
      pf.u[1] = cvtpk(sA[4 * kk + 2], sA[4 * kk + 3]);
      pf.u[2] = cvtpk(sB[4 * kk + 0], sB[4 * kk + 1]);
      pf.u[3] = cvtpk(sB[4 * kk + 2], sB[4 * kk + 3]);
      bf16x8 vf0 = *(const bf16x8*)(bk + (kk * 2 + 0) * 1024 + loff);
      bf16x8 vf1 = *(const bf16x8*)(bk + (kk * 2 + 1) * 1024 + loff);
      bf16x8 of  = *(const bf16x8*)(mrowt + (2 * kk + hi) * 8);
      accO0 = __builtin_amdgcn_mfma_f32_32x32x16_bf16(pf.v, vf0, accO0, 0, 0, 0);
      accO1 = __builtin_amdgcn_mfma_f32_32x32x16_bf16(pf.v, vf1, accO1, 0, 0, 0);
      acc2  = __builtin_amdgcn_mfma_f32_32x32x16_bf16(pf.v, of,  acc2,  0, 0, 0);
    }
    cur ^= 1;
  }

  // ---- epilogue: O / l ; l sits lane-aligned in acc2 (no shuffles) ----
  #pragma unroll
  for (int reg = 0; reg < 16; ++reg) {
    int ql = (reg & 3) + 8 * (reg >> 2) + 4 * hi;
    float iq = 1.0f / acc2[reg];
    float* orow = Og + base + (size_t)(q0 + ql) * DD;
    orow[l31]      = accO0[reg] * iq;
    orow[32 + l31] = accO1[reg] * iq;
  }
}

// ---------------- fallback (no-ws path) ----------------
__global__ __launch_bounds__(256)
void attn_fallback(const float* __restrict__ Qg, const float* __restrict__ Kg,
                   const float* __restrict__ Vg, const int* __restrict__ maskg,
                   float* __restrict__ Og)
{
  __shared__ short ktf[KVB][72];
  __shared__ short vtf[DD][72];
  __shared__ short ptf[4][16][72];
  __shared__ float bias_s[KVB];

  const int tid = threadIdx.x, wv = tid >> 6, lane = tid & 63;
  const int l15 = lane & 15, lg = lane >> 4;
  const int bh = blockIdx.y, bb = bh >> 4, q0 = blockIdx.x * 64;
  const size_t base = (size_t)bh * SQ * DD;
  const f32x4 zero4 = {0.f, 0.f, 0.f, 0.f};

  bf16x8 qf[2];
  {
    const float* qrow = Qg + base + (size_t)(q0 + wv * 16 + l15) * DD + lg * 8;
    #pragma unroll
    for (int kf = 0; kf < 2; ++kf) {
      float tv[8];
      *(f32x4*)&tv[0] = *(const f32x4*)&qrow[kf * 32];
      *(f32x4*)&tv[4] = *(const f32x4*)&qrow[kf * 32 + 4];
      #pragma unroll
      for (int j = 0; j < 8; ++j) qf[kf][j] = f2bf(tv[j]);
    }
  }
  f32x4 oacc[4];
  #pragma unroll
  for (int d = 0; d < 4; ++d) oacc[d] = zero4;
  float mrun[4] = {-3e38f, -3e38f, -3e38f, -3e38f};
  float lrun[4] = {0.f, 0.f, 0.f, 0.f};

  for (int kv0 = 0; kv0 < SQ; kv0 += KVB) {
    __syncthreads();
    {
      int r = tid >> 2, c0 = (tid & 3) * 16;
      const float* g = Kg + base + (size_t)(kv0 + r) * DD + c0;
      float tv[16];
      #pragma unroll
      for (int i = 0; i < 4; ++i) *(f32x4*)&tv[i * 4] = *(const f32x4*)&g[i * 4];
      bf16x8 a, b2;
      #pragma unroll
      for (int j = 0; j < 8; ++j) { a[j] = f2bf(tv[j]); b2[j] = f2bf(tv[8 + j]); }
      *(bf16x8*)&ktf[r][c0] = a;
      *(bf16x8*)&ktf[r][c0 + 8] = b2;
    }
    {
      int r = tid & 63, c0 = (tid >> 6) * 16;
      const float* g = Vg + base + (size_t)(kv0 + r) * DD + c0;
      float tv[16];
      #pragma unroll
      for (int i = 0; i < 4; ++i) *(f32x4*)&tv[i * 4] = *(const f32x4*)&g[i * 4];
      #pragma unroll
      for (int j = 0; j < 16; ++j) vtf[c0 + j][r] = f2bf(tv[j]);
    }
    if (tid < KVB) bias_s[tid] = maskg[(size_t)bb * SQ + kv0 + tid] ? -1e9f : 0.f;
    __syncthreads();

    f32x4 acc[4];
    #pragma unroll
    for (int n = 0; n < 4; ++n) acc[n] = zero4;
    #pragma unroll
    for (int n = 0; n < 4; ++n) {
      bf16x8 k0 = *(const bf16x8*)&ktf[n * 16 + l15][lg * 8];
      bf16x8 k1 = *(const bf16x8*)&ktf[n * 16 + l15][32 + lg * 8];
      acc[n] = __builtin_amdgcn_mfma_f32_16x16x32_bf16(qf[0], k0, acc[n], 0, 0, 0);
      acc[n] = __builtin_amdgcn_mfma_f32_16x16x32_bf16(qf[1], k1, acc[n], 0, 0, 0);
    }
    float brow[4];
    #pragma unroll
    for (int n = 0; n < 4; ++n) brow[n] = bias_s[n * 16 + l15];
    #pragma unroll
    for (int reg = 0; reg < 4; ++reg) {
      float s0 = acc[0][reg] * 0.125f + brow[0];
      float s1 = acc[1][reg] * 0.125f + brow[1];
      float s2 = acc[2][reg] * 0.125f + brow[2];
      float s3 = acc[3][reg] * 0.125f + brow[3];
      float tm = fmaxf(fmaxf(s0, s1), fmaxf(s2, s3));
      #pragma unroll
      for (int off = 1; off < 16; off <<= 1) tm = fmaxf(tm, __shfl_xor(tm, off, 64));
      float mnew = fmaxf(mrun[reg], tm);
      float scale = __expf(mrun[reg] - mnew);
      float p0 = __expf(s0 - mnew), p1 = __expf(s1 - mnew);
      float p2 = __expf(s2 - mnew), p3 = __expf(s3 - mnew);
      float rs = (p0 + p1) + (p2 + p3);
      #pragma unroll
      for (int off = 1; off < 16; off <<= 1) rs += __shfl_xor(rs, off, 64);
      lrun[reg] = lrun[reg] * scale + rs;
      mrun[reg] = mnew;
      #pragma unroll
      for (int d = 0; d < 4; ++d) oacc[d][reg] *= scale;
      int prow = lg * 4 + reg;
      ptf[wv][prow][     l15] = f2bf(p0);
      ptf[wv][prow][16 + l15] = f2bf(p1);
      ptf[wv][prow][32 + l15] = f2bf(p2);
      ptf[wv][prow][48 + l15] = f2bf(p3);
    }
    bf16x8 pf0 = *(const bf16x8*)&ptf[wv][l15][lg * 8];
    bf16x8 pf1 = *(const bf16x8*)&ptf[wv][l15][32 + lg * 8];
    #pragma unroll
    for (int d = 0; d < 4; ++d) {
      bf16x8 v0 = *(const bf16x8*)&vtf[d * 16 + l15][lg * 8];
      bf16x8 v1 = *(const bf16x8*)&vtf[d * 16 + l15][32 + lg * 8];
      oacc[d] = __builtin_amdgcn_mfma_f32_16x16x32_bf16(pf0, v0, oacc[d], 0, 0, 0);
      oacc[d] = __builtin_amdgcn_mfma_f32_16x16x32_bf16(pf1, v1, oacc[d], 0, 0, 0);
    }
  }
  #pragma unroll
  for (int reg = 0; reg < 4; ++reg) {
    float inv = 1.0f / lrun[reg];
    int row = q0 + wv * 16 + lg * 4 + reg;
    float* orow = Og + base + (size_t)row * DD;
    #pragma unroll
    for (int d = 0; d < 4; ++d) orow[d * 16 + l15] = oacc[d][reg] * inv;
  }
}

extern "C" void kernel_launch(void* const* d_in, const int* in_sizes, int n_in,
                              void* d_out, int out_size, void* d_ws, size_t ws_size,
                              hipStream_t stream) {
  const float* q    = (const float*)d_in[0];
  const float* k    = (const float*)d_in[1];
  const float* v    = (const float*)d_in[2];
  const int*   mask = (const int*)d_in[3];
  float* out = (float*)d_out;

  const size_t need = (size_t)NBH * NT * REC;   // 32 MiB
  if (ws_size >= need) {
    char* img = (char*)d_ws;
    dim3 pgrid(NT, NBH);
    prepack<<<pgrid, 256, 0, stream>>>(k, v, mask, img);
    attn32<<<dim3(1024), 256, 0, stream>>>(img, q, mask, out);
  } else {
    dim3 grid(SQ / 64, NBH);
    attn_fallback<<<grid, 256, 0, stream>>>(q, k, v, mask, out);
  }
}

// Round 18
// 122.702 us; speedup vs baseline: 1.0021x; 1.0021x over previous
//
#include <hip/hip_runtime.h>
#include <hip/hip_bf16.h>

#define SQ 2048
#define DD 64
#define NBH 64            // B*H
#define KVB 64
#define NT (SQ / KVB)     // 32 kv tiles
#define REC 16384         // per-(bh,tile): [K 8KB (8 chunks) | V 8KB (8 chunks)]
#define VOFF 8192
#define STG 8192          // staged bytes per tile (V only)
#define SCL 0.18033688011112042f   // 0.125 * log2(e); folded into Q

typedef __attribute__((ext_vector_type(8))) short bf16x8;
typedef __attribute__((ext_vector_type(4))) float f32x4;
typedef __attribute__((ext_vector_type(16))) float f32x16;

__device__ __forceinline__ short f2bf(float f) {
  union { float f; unsigned u; } un; un.f = f;
  unsigned r = un.u + 0x7fffu + ((un.u >> 16) & 1u);   // RNE
  return (short)(r >> 16);
}

__device__ __forceinline__ unsigned cvtpk(float lo, float hi) {
  unsigned d;
  asm("v_cvt_pk_bf16_f32 %0, %1, %2" : "=v"(d) : "v"(lo), "v"(hi));
  return d;
}

__device__ __forceinline__ void gld_lds16(const void* g, void* l) {
  __builtin_amdgcn_global_load_lds(
      (const __attribute__((address_space(1))) unsigned int*)g,
      (__attribute__((address_space(3))) unsigned int*)l, 16, 0, 0);
}

__device__ __forceinline__ f32x16 z16() {
  f32x16 z;
  #pragma unroll
  for (int i = 0; i < 16; ++i) z[i] = 0.f;
  return z;
}

// Record layout (load-order-major, per (bh,t)):
//   K chunk c = h*4+kk (0..7) at c*1024:  lane(l31,hi)*16B = bf16 K[h*32+l31][(2kk+hi)*8+j]
//   V chunk cid=kk*2+h (0..7) at 8192+cid*1024: lane(l31,hi)*16B =
//       bf16 V[kv][h*32+l31] (masked->0), kv = 8kk + 4hi + (j&3) + 32*(j>>2)
// All wave accesses (global or LDS) are contiguous 1KB at lane*16 -> conflict-free.

// ---------------- prepass: K,V fp32 -> load-order-major bf16 records ----------------
__global__ __launch_bounds__(256)
void prepack(const float* __restrict__ Kg, const float* __restrict__ Vg,
             const int* __restrict__ maskg, char* __restrict__ img)
{
  __shared__ float vst[64][68];
  const int bh = blockIdx.y, t = blockIdx.x;
  const size_t base = ((size_t)bh * SQ + (size_t)t * KVB) * DD;
  const int tid  = threadIdx.x;
  const int wv   = tid >> 6;
  const int lane = tid & 63;
  const int l31  = lane & 31;
  const int hi   = lane >> 5;
  char* rec = img + ((size_t)bh * NT + t) * REC;
  const int* mrow = maskg + (size_t)(bh >> 4) * SQ + t * KVB;
  unsigned long long mb = __ballot(mrow[lane] != 0);

  // stage V tile fp32 into LDS (coalesced)
  {
    int r = tid >> 2, c0 = (tid & 3) * 16;
    const float* g = Vg + base + (size_t)r * DD + c0;
    #pragma unroll
    for (int i = 0; i < 4; ++i)
      *(f32x4*)&vst[r][c0 + i * 4] = *(const f32x4*)&g[i * 4];
  }
  // K chunks: flat index c = wv*2 + i; h = c>>2, kk = c&3
  #pragma unroll
  for (int i = 0; i < 2; ++i) {
    int c = wv * 2 + i;            // 0..7
    int h = c >> 2, kk = c & 3;
    int r = h * 32 + l31;
    int col = (2 * kk + hi) * 8;
    const float* g = Kg + base + (size_t)r * DD + col;
    float tv[8];
    *(f32x4*)&tv[0] = *(const f32x4*)&g[0];
    *(f32x4*)&tv[4] = *(const f32x4*)&g[4];
    bf16x8 o;
    #pragma unroll
    for (int j = 0; j < 8; ++j) o[j] = f2bf(tv[j]);
    *(bf16x8*)(rec + c * 1024 + lane * 16) = o;
  }
  __syncthreads();
  // V chunks (kv-permuted, masked -> 0) -- verbatim R12/R13 layout
  #pragma unroll
  for (int i = 0; i < 2; ++i) {
    int cid = wv * 2 + i;          // 0..7
    int kk = cid >> 1, h = cid & 1;
    int d = h * 32 + l31;
    bf16x8 o;
    #pragma unroll
    for (int j = 0; j < 8; ++j) {
      int kv = 8 * kk + 4 * hi + (j & 3) + 32 * (j >> 2);
      o[j] = ((mb >> kv) & 1ull) ? (short)0 : f2bf(vst[kv][d]);
    }
    *(bf16x8*)(rec + VOFF + cid * 1024 + lane * 16) = o;
  }
}

// ---------------- main: all-K reg prefetch, V-only LDS dbuf, R13 barrier discipline ----------------
__global__ __launch_bounds__(256, 4)
void attn32(const char* __restrict__ img, const float* __restrict__ Qg,
            const int* __restrict__ maskg, float* __restrict__ Og)
{
  __shared__ char buf[2][STG];                     // V x2 = 16KB
  __shared__ __align__(16) short mones[NT][KVB];   // permuted per-tile ones/mask rows

  const int tid  = threadIdx.x;
  const int wv   = tid >> 6;
  const int lane = tid & 63;
  const int l31  = lane & 31;
  const int hi   = lane >> 5;

  // XCD-aware swizzle: 1024 blocks, 8 XCDs -> 128-block chunks (8 bh per XCD)
  const int bid = blockIdx.x;
  const int swz = (bid & 7) * 128 + (bid >> 3);
  const int qb = swz & 15;
  const int bh = swz >> 4;
  const int q0 = qb * 128 + wv * 32;
  const size_t base = (size_t)bh * SQ * DD;
  const char* rec0 = img + (size_t)bh * NT * REC;

  // ---- build permuted per-tile ones rows from mask (once per block) ----
  {
    const int* mrow = maskg + (size_t)(bh >> 4) * SQ;
    #pragma unroll
    for (int i = 0; i < 8; ++i) {
      int idx = tid + i * 256;           // 0..2047
      int t = idx >> 6, p = idx & 63;
      int kv = 8 * (p >> 4) + 4 * ((p >> 3) & 1) + (p & 3) + 32 * ((p >> 2) & 1);
      mones[t][p] = mrow[t * KVB + kv] ? (short)0 : (short)0x3F80;
    }
  }

  // Q fragments pre-scaled by SCL (B-operand: n = l31, k-slot j <-> d = kk*16 + hi*8 + j)
  bf16x8 qf[4];
  {
    const float* qrow = Qg + base + (size_t)(q0 + l31) * DD + hi * 8;
    #pragma unroll
    for (int kk = 0; kk < 4; ++kk) {
      float tv[8];
      *(f32x4*)&tv[0] = *(const f32x4*)&qrow[kk * 16];
      *(f32x4*)&tv[4] = *(const f32x4*)&qrow[kk * 16 + 4];
      #pragma unroll
      for (int j = 0; j < 8; ++j) qf[kk][j] = f2bf(tv[j] * SCL);
    }
  }

  const int loff = lane * 16;

  // prologue: all K of tile 0 into regs; stage V of tile 0 into buf0
  bf16x8 kreg[8];
  #pragma unroll
  for (int c = 0; c < 8; ++c)
    kreg[c] = *(const bf16x8*)(rec0 + c * 1024 + loff);
  #pragma unroll
  for (int i = 0; i < 2; ++i)
    gld_lds16(rec0 + VOFF + i * 4096 + tid * 16, buf[0] + i * 4096 + tid * 16);

  f32x16 accO0 = z16(), accO1 = z16(), acc2 = z16();

  int cur = 0;
  for (int t = 0; t < NT; ++t) {
    __syncthreads();   // buf[cur] staged (vmcnt drain); prior reads of buf[cur^1] done

    if (t + 1 < NT) {  // stage next V into the buffer prev PV finished with
      const char* rec = rec0 + (size_t)(t + 1) * REC;
      char* dst = buf[cur ^ 1];
      #pragma unroll
      for (int i = 0; i < 2; ++i)
        gld_lds16(rec + VOFF + i * 4096 + tid * 16, dst + i * 4096 + tid * 16);
    }

    // ---- S^T = K Q^T : entirely from registers ----
    f32x16 sA = z16(), sB = z16();
    #pragma unroll
    for (int kk = 0; kk < 4; ++kk) {
      sA = __builtin_amdgcn_mfma_f32_32x32x16_bf16(kreg[kk],     qf[kk], sA, 0, 0, 0);
      sB = __builtin_amdgcn_mfma_f32_32x32x16_bf16(kreg[4 + kk], qf[kk], sB, 0, 0, 0);
    }

    // ---- prefetch next tile's K into regs (window: exp2 + PV) ----
    if (t + 1 < NT) {
      const char* rec = rec0 + (size_t)(t + 1) * REC;
      #pragma unroll
      for (int c = 0; c < 8; ++c)
        kreg[c] = *(const bf16x8*)(rec + c * 1024 + loff);
    }

    // ---- P = exp2(s), static max folded away (exact 2^k shift cancels in O/l) ----
    #pragma unroll
    for (int r = 0; r < 16; ++r) {
      sA[r] = exp2f(sA[r]);
      sB[r] = exp2f(sB[r]);
    }

    // ---- PV + l-channel: A-fragment lane-local; V chunks linear in LDS ----
    const char* bk = buf[cur];
    const short* mrowt = &mones[t][0];
    #pragma unroll
    for (int kk = 0; kk < 4; ++kk) {
      union { unsigned u[4]; bf16x8 v; } pf;
      pf.u[0] = cvtpk(sA[4 * kk + 0], sA[4 * kk + 1]);
      pf.u[1] = cvtpk(sA[4 * kk + 2], sA[4 * kk + 3]);
      pf.u[2] = cvtpk(sB[4 * kk + 0], sB[4 * kk + 1]);
      pf.u[3] = cvtpk(sB[4 * kk + 2], sB[4 * kk + 3]);
      bf16x8 vf0 = *(const bf16x8*)(bk + (kk * 2 + 0) * 1024 + loff);
      bf16x8 vf1 = *(const bf16x8*)(bk + (kk * 2 + 1) * 1024 + loff);
      bf16x8 of  = *(const bf16x8*)(mrowt + (2 * kk + hi) * 8);
      accO0 = __builtin_amdgcn_mfma_f32_32x32x16_bf16(pf.v, vf0, accO0, 0, 0, 0);
      accO1 = __builtin_amdgcn_mfma_f32_32x32x16_bf16(pf.v, vf1, accO1, 0, 0, 0);
      acc2  = __builtin_amdgcn_mfma_f32_32x32x16_bf16(pf.v, of,  acc2,  0, 0, 0);
    }
    cur ^= 1;
  }

  // ---- epilogue: O / l ; l sits lane-aligned in acc2 (no shuffles) ----
  #pragma unroll
  for (int reg = 0; reg < 16; ++reg) {
    int ql = (reg & 3) + 8 * (reg >> 2) + 4 * hi;
    float iq = 1.0f / acc2[reg];
    float* orow = Og + base + (size_t)(q0 + ql) * DD;
    orow[l31]      = accO0[reg] * iq;
    orow[32 + l31] = accO1[reg] * iq;
  }
}

// ---------------- fallback (no-ws path) ----------------
__global__ __launch_bounds__(256)
void attn_fallback(const float* __restrict__ Qg, const float* __restrict__ Kg,
                   const float* __restrict__ Vg, const int* __restrict__ maskg,
                   float* __restrict__ Og)
{
  __shared__ short ktf[KVB][72];
  __shared__ short vtf[DD][72];
  __shared__ short ptf[4][16][72];
  __shared__ float bias_s[KVB];

  const int tid = threadIdx.x, wv = tid >> 6, lane = tid & 63;
  const int l15 = lane & 15, lg = lane >> 4;
  const int bh = blockIdx.y, bb = bh >> 4, q0 = blockIdx.x * 64;
  const size_t base = (size_t)bh * SQ * DD;
  const f32x4 zero4 = {0.f, 0.f, 0.f, 0.f};

  bf16x8 qf[2];
  {
    const float* qrow = Qg + base + (size_t)(q0 + wv * 16 + l15) * DD + lg * 8;
    #pragma unroll
    for (int kf = 0; kf < 2; ++kf) {
      float tv[8];
      *(f32x4*)&tv[0] = *(const f32x4*)&qrow[kf * 32];
      *(f32x4*)&tv[4] = *(const f32x4*)&qrow[kf * 32 + 4];
      #pragma unroll
      for (int j = 0; j < 8; ++j) qf[kf][j] = f2bf(tv[j]);
    }
  }
  f32x4 oacc[4];
  #pragma unroll
  for (int d = 0; d < 4; ++d) oacc[d] = zero4;
  float mrun[4] = {-3e38f, -3e38f, -3e38f, -3e38f};
  float lrun[4] = {0.f, 0.f, 0.f, 0.f};

  for (int kv0 = 0; kv0 < SQ; kv0 += KVB) {
    __syncthreads();
    {
      int r = tid >> 2, c0 = (tid & 3) * 16;
      const float* g = Kg + base + (size_t)(kv0 + r) * DD + c0;
      float tv[16];
      #pragma unroll
      for (int i = 0; i < 4; ++i) *(f32x4*)&tv[i * 4] = *(const f32x4*)&g[i * 4];
      bf16x8 a, b2;
      #pragma unroll
      for (int j = 0; j < 8; ++j) { a[j] = f2bf(tv[j]); b2[j] = f2bf(tv[8 + j]); }
      *(bf16x8*)&ktf[r][c0] = a;
      *(bf16x8*)&ktf[r][c0 + 8] = b2;
    }
    {
      int r = tid & 63, c0 = (tid >> 6) * 16;
      const float* g = Vg + base + (size_t)(kv0 + r) * DD + c0;
      float tv[16];
      #pragma unroll
      for (int i = 0; i < 4; ++i) *(f32x4*)&tv[i * 4] = *(const f32x4*)&g[i * 4];
      #pragma unroll
      for (int j = 0; j < 16; ++j) vtf[c0 + j][r] = f2bf(tv[j]);
    }
    if (tid < KVB) bias_s[tid] = maskg[(size_t)bb * SQ + kv0 + tid] ? -1e9f : 0.f;
    __syncthreads();

    f32x4 acc[4];
    #pragma unroll
    for (int n = 0; n < 4; ++n) acc[n] = zero4;
    #pragma unroll
    for (int n = 0; n < 4; ++n) {
      bf16x8 k0 = *(const bf16x8*)&ktf[n * 16 + l15][lg * 8];
      bf16x8 k1 = *(const bf16x8*)&ktf[n * 16 + l15][32 + lg * 8];
      acc[n] = __builtin_amdgcn_mfma_f32_16x16x32_bf16(qf[0], k0, acc[n], 0, 0, 0);
      acc[n] = __builtin_amdgcn_mfma_f32_16x16x32_bf16(qf[1], k1, acc[n], 0, 0, 0);
    }
    float brow[4];
    #pragma unroll
    for (int n = 0; n < 4; ++n) brow[n] = bias_s[n * 16 + l15];
    #pragma unroll
    for (int reg = 0; reg < 4; ++reg) {
      float s0 = acc[0][reg] * 0.125f + brow[0];
      float s1 = acc[1][reg] * 0.125f + brow[1];
      float s2 = acc[2][reg] * 0.125f + brow[2];
      float s3 = acc[3][reg] * 0.125f + brow[3];
      float tm = fmaxf(fmaxf(s0, s1), fmaxf(s2, s3));
      #pragma unroll
      for (int off = 1; off < 16; off <<= 1) tm = fmaxf(tm, __shfl_xor(tm, off, 64));
      float mnew = fmaxf(mrun[reg], tm);
      float scale = __expf(mrun[reg] - mnew);
      float p0 = __expf(s0 - mnew), p1 = __expf(s1 - mnew);
      float p2 = __expf(s2 - mnew), p3 = __expf(s3 - mnew);
      float rs = (p0 + p1) + (p2 + p3);
      #pragma unroll
      for (int off = 1; off < 16; off <<= 1) rs += __shfl_xor(rs, off, 64);
      lrun[reg] = lrun[reg] * scale + rs;
      mrun[reg] = mnew;
      #pragma unroll
      for (int d = 0; d < 4; ++d) oacc[d][reg] *= scale;
      int prow = lg * 4 + reg;
      ptf[wv][prow][     l15] = f2bf(p0);
      ptf[wv][prow][16 + l15] = f2bf(p1);
      ptf[wv][prow][32 + l15] = f2bf(p2);
      ptf[wv][prow][48 + l15] = f2bf(p3);
    }
    bf16x8 pf0 = *(const bf16x8*)&ptf[wv][l15][lg * 8];
    bf16x8 pf1 = *(const bf16x8*)&ptf[wv][l15][32 + lg * 8];
    #pragma unroll
    for (int d = 0; d < 4; ++d) {
      bf16x8 v0 = *(const bf16x8*)&vtf[d * 16 + l15][lg * 8];
      bf16x8 v1 = *(const bf16x8*)&vtf[d * 16 + l15][32 + lg * 8];
      oacc[d] = __builtin_amdgcn_mfma_f32_16x16x32_bf16(pf0, v0, oacc[d], 0, 0, 0);
      oacc[d] = __builtin_amdgcn_mfma_f32_16x16x32_bf16(pf1, v1, oacc[d], 0, 0, 0);
    }
  }
  #pragma unroll
  for (int reg = 0; reg < 4; ++reg) {
    float inv = 1.0f / lrun[reg];
    int row = q0 + wv * 16 + lg * 4 + reg;
    float* orow = Og + base + (size_t)row * DD;
    #pragma unroll
    for (int d = 0; d < 4; ++d) orow[d * 16 + l15] = oacc[d][reg] * inv;
  }
}

extern "C" void kernel_launch(void* const* d_in, const int* in_sizes, int n_in,
                              void* d_out, int out_size, void* d_ws, size_t ws_size,
                              hipStream_t stream) {
  const float* q    = (const float*)d_in[0];
  const float* k    = (const float*)d_in[1];
  const float* v    = (const float*)d_in[2];
  const int*   mask = (const int*)d_in[3];
  float* out = (float*)d_out;

  const size_t need = (size_t)NBH * NT * REC;   // 32 MiB
  if (ws_size >= need) {
    char* img = (char*)d_ws;
    dim3 pgrid(NT, NBH);
    prepack<<<pgrid, 256, 0, stream>>>(k, v, mask, img);
    attn32<<<dim3(1024), 256, 0, stream>>>(img, q, mask, out);
  } else {
    dim3 grid(SQ / 64, NBH);
    attn_fallback<<<grid, 256, 0, stream>>>(q, k, v, mask, out);
  }
}